// Round 1
// baseline (2071.508 us; speedup 1.0000x reference)
//
#include <hip/hip_runtime.h>

#define CC 56
#define TT 64
#define GRID 1024            // prologue blocks (one row each)
#define LBLK 256             // recurrent-loop blocks (4 rows each)
#define NT 64                // single wave per block
#define NFLAG 64
#define SS 32                // 128 B stride between sync slots
#define FB (GRID * SS)       // flag base (int index)
#define AGENT __HIP_MEMORY_SCOPE_AGENT

// ---- ws byte offsets
#define OFF_FWS   147456     // carry vectors (floats)
#define OFF_W1BF  262144     // W1 bf16, 2 MB
#define OFF_W2BF  2359296    // W2 bf16, 2 MB
#define OFF_PRIV  4456448    // 1024 x 32 KB private regions
#define PRIVB     32768

// ---- private region offsets (ushort units)
#define PM2  0               // M2 rows (i,g,o) 3x1024 bf16
#define PM3  3072
#define PW1R 6144            // Wi1 right-half rows
#define PW2R 9216            // Wi2 right-half rows
#define PV2  12288
#define PV3  13312
#define PV1  14336
#define PA0  15360           // byte 30720: A0 fp32 3x56
#define PCS  15696           // byte 31392: cs1[3] cs2[3] cs3[3] fp32

// ---- fws float offsets (all coherent)
#define FS1   0
#define FS2   1024
#define FS3   2048
#define FTD1  3072           // two parity slots 3072/4096
#define FTD2  5120           // two parity slots 5120/6144
#define FRC1  7168           // 64

static __device__ __forceinline__ float wredsum(float v) {
#pragma unroll
  for (int m = 32; m; m >>= 1) v += __shfl_xor(v, m, 64);
  return v;
}
static __device__ __forceinline__ float sigm(float x) { return 1.f / (1.f + __expf(-x)); }
static __device__ __forceinline__ float ftanh(float x) {
  x = fminf(15.f, fmaxf(-15.f, x));
  float e = __expf(2.f * x);
  return (e - 1.f) / (e + 1.f);
}

// coherent accessors (agent-scope, L2-bypassing) for cross-XCD data
static __device__ __forceinline__ float2 cld2(const float* p) {
  unsigned long long u = __hip_atomic_load((const unsigned long long*)p, __ATOMIC_RELAXED, AGENT);
  union { unsigned long long u; float2 f; } c; c.u = u; return c.f;
}
static __device__ __forceinline__ float4 cld4(const float* p) {
  float2 a = cld2(p), b = cld2(p + 2);
  return make_float4(a.x, a.y, b.x, b.y);
}
static __device__ __forceinline__ float cld1(const float* p) {
  return __uint_as_float(__hip_atomic_load((const unsigned int*)p, __ATOMIC_RELAXED, AGENT));
}
static __device__ __forceinline__ void cst1(float* p, float v) {
  __hip_atomic_store((unsigned int*)p, __float_as_uint(v), __ATOMIC_RELAXED, AGENT);
}
static __device__ __forceinline__ void cstu2(unsigned* p, unsigned a, unsigned b) {
  unsigned long long u = (unsigned long long)a | ((unsigned long long)b << 32);
  __hip_atomic_store((unsigned long long*)p, u, __ATOMIC_RELAXED, AGENT);
}
static __device__ __forceinline__ int ldi(const int* p) {
  return __hip_atomic_load(p, __ATOMIC_RELAXED, AGENT);
}
static __device__ __forceinline__ void sti(int* p, int v) {
  __hip_atomic_store(p, v, __ATOMIC_RELAXED, AGENT);
}

// bf16 pack (RNE) + dot helpers
static __device__ __forceinline__ unsigned bfp(float lo, float hi) {
  unsigned a = __float_as_uint(lo), b = __float_as_uint(hi);
  a = (a + 0x7fffu + ((a >> 16) & 1u)) >> 16;
  b = (b + 0x7fffu + ((b >> 16) & 1u)) >> 16;
  return a | (b << 16);
}
static __device__ __forceinline__ float blo(unsigned u) { return __uint_as_float(u << 16); }
static __device__ __forceinline__ float bhi(unsigned u) { return __uint_as_float(u & 0xffff0000u); }
static __device__ __forceinline__ float bdot4(uint4 w, float4 a, float4 b) {
  float r =  blo(w.x) * a.x;
  r = fmaf(bhi(w.x), a.y, r);
  r = fmaf(blo(w.y), a.z, r);
  r = fmaf(bhi(w.y), a.w, r);
  r = fmaf(blo(w.z), b.x, r);
  r = fmaf(bhi(w.z), b.y, r);
  r = fmaf(blo(w.w), b.z, r);
  r = fmaf(bhi(w.w), b.w, r);
  return r;
}
static __device__ __forceinline__ float asum4(float4 v) {
  return fabsf(v.x) + fabsf(v.y) + fabsf(v.z) + fabsf(v.w);
}

// 16-elem/lane full-wave dot against bf16 weight row (2 x uint4 per lane)
#define DOT16(base, qoff, A, B, C, D)                                   \
  ({ const uint4* _w = (const uint4*)(base);                            \
     uint4 _qa = _w[(qoff) + 2 * lane];                                 \
     uint4 _qb = _w[(qoff) + 2 * lane + 1];                             \
     wredsum(bdot4(_qa, A, B) + bdot4(_qb, C, D)); })

// master-relay barrier (verified scheme). No init: 0xAA poison < 0, g monotone > 0.
// warr: __syncthreads forces vmcnt(0) drain of prior agent stores before arrive.
static __device__ __forceinline__ void warr(int* iws, int g, int b) {
  __syncthreads();
  if (threadIdx.x == 0) sti(iws + SS * b, g);
}
// nsl = arrive slots per lane for the master: 16 for 1024-wide (g<=2), 4 for 256-wide
static __device__ __forceinline__ void wwait(int* iws, int g, int b, int nsl) {
  const int lane = threadIdx.x;
  if (b == 0) {
    const int* p0 = iws + SS * lane * nsl;
    for (;;) {
      int ok = 1;
      for (int s = 0; s < nsl; ++s) ok &= (ldi(p0 + SS * s) >= g);
      if (ok) break;
      __builtin_amdgcn_s_sleep(1);
    }
    __syncthreads();
    sti(iws + FB + SS * lane, g);          // 64 flags by 64 lanes
  } else {
    if (lane == 0)
      while (ldi(iws + FB + SS * (b & (NFLAG - 1))) < g) __builtin_amdgcn_s_sleep(1);
  }
  __asm__ __volatile__("" ::: "memory");
  __syncthreads();
}

// 1024-dot, full wave, 16 fp32/lane (prologue constants)
static __device__ __forceinline__ float dotw(const float* a, const float* c, int lane) {
  const float4* a4 = (const float4*)a;
  const float4* c4 = (const float4*)c;
  float acc = 0.f;
#pragma unroll
  for (int j = 0; j < 4; ++j) {
    float4 x = a4[lane * 4 + j], y = c4[lane * 4 + j];
    acc = fmaf(x.x, y.x, fmaf(x.y, y.y, fmaf(x.z, y.z, fmaf(x.w, y.w, acc))));
  }
  return wredsum(acc);
}

// prologue GEMM: 3 LDS rows x bf16 matrix -> 3x16 cols/lane, bf16 out (agent stores)
static __device__ __forceinline__ void gemm48(const uint4* wsrc, const float* r0, const float* r1,
                                              const float* r2, unsigned short* dst, int lane) {
  float ac[48];
#pragma unroll
  for (int i = 0; i < 48; ++i) ac[i] = 0.f;
#pragma unroll 2
  for (int k = 0; k < 1024; ++k) {
    uint4 qa = wsrc[k * 128 + 2 * lane];
    uint4 qb = wsrc[k * 128 + 2 * lane + 1];
    float fv[16];
    fv[0] = blo(qa.x);  fv[1] = bhi(qa.x);  fv[2] = blo(qa.y);  fv[3] = bhi(qa.y);
    fv[4] = blo(qa.z);  fv[5] = bhi(qa.z);  fv[6] = blo(qa.w);  fv[7] = bhi(qa.w);
    fv[8] = blo(qb.x);  fv[9] = bhi(qb.x);  fv[10] = blo(qb.y); fv[11] = bhi(qb.y);
    fv[12] = blo(qb.z); fv[13] = bhi(qb.z); fv[14] = blo(qb.w); fv[15] = bhi(qb.w);
    float ai = r0[k], ag = r1[k], ao = r2[k];
#pragma unroll
    for (int c = 0; c < 16; ++c) {
      ac[c]      = fmaf(ai, fv[c], ac[c]);
      ac[16 + c] = fmaf(ag, fv[c], ac[16 + c]);
      ac[32 + c] = fmaf(ao, fv[c], ac[32 + c]);
    }
  }
#pragma unroll
  for (int gg = 0; gg < 3; ++gg) {
    unsigned* d = (unsigned*)(dst + gg * 1024);
#pragma unroll
    for (int u = 0; u < 4; ++u)
      cstu2(d + 8 * lane + 2 * u,
            bfp(ac[gg * 16 + 4 * u], ac[gg * 16 + 4 * u + 1]),
            bfp(ac[gg * 16 + 4 * u + 2], ac[gg * 16 + 4 * u + 3]));
  }
}

__global__ void __launch_bounds__(NT, 1) predcells(
    const float* __restrict__ inp,
    const float* __restrict__ W0w, const float* __restrict__ W0b,
    const float* __restrict__ W1w, const float* __restrict__ W1b,
    const float* __restrict__ W2w, const float* __restrict__ W2b,
    const float* __restrict__ Wi1, const float* __restrict__ b1,
    const float* __restrict__ Wi2, const float* __restrict__ b2,
    const float* __restrict__ Wi3, const float* __restrict__ b3,
    const float* __restrict__ V1w, const float* __restrict__ V1b,
    const float* __restrict__ V2w, const float* __restrict__ V2b,
    const float* __restrict__ V3w, const float* __restrict__ V3b,
    const int* __restrict__ itn,
    float* __restrict__ out, char* ws)
{
  const int lane = threadIdx.x;        // 0..63, single wave
  const int b = blockIdx.x;

  int* iws = (int*)ws;
  float* fws = (float*)(ws + OFF_FWS);
  unsigned short* w1bf = (unsigned short*)(ws + OFF_W1BF);
  unsigned short* w2bf = (unsigned short*)(ws + OFF_W2BF);
  unsigned short* priv = (unsigned short*)(ws + OFF_PRIV + (size_t)b * PRIVB);

  __shared__ float arow[6][1024];      // prologue GEMM staging (24 KB)

  const float lam = (itn[0] <= 1000) ? 1e-4f : 1e-2f;
  const float lam2 = lam * lam;
  float l0 = 0.f, l1 = 0.f, l2 = 0.f;  // loss partials (block0)

  // ======== phase 0: W1/W2 row b -> bf16 (agent stores; read by other blocks)
  {
    const float4* r1 = (const float4*)(W1w + (size_t)b * 1024);
    const float4* r2 = (const float4*)(W2w + (size_t)b * 1024);
    unsigned* d1 = (unsigned*)(w1bf + (size_t)b * 1024);
    unsigned* d2 = (unsigned*)(w2bf + (size_t)b * 1024);
#pragma unroll
    for (int u = 0; u < 4; ++u) {
      float4 a = r1[lane * 4 + u];
      cstu2(d1 + 2 * (lane * 4 + u), bfp(a.x, a.y), bfp(a.z, a.w));
      float4 c = r2[lane * 4 + u];
      cstu2(d2 + 2 * (lane * 4 + u), bfp(c.x, c.y), bfp(c.z, c.w));
    }
  }
  warr(iws, 1, b);

  // ======== phase 1 (during barrier-1 window): per-row constants + private weights
  float c1r[3], c2r[3], c3r[3];
#pragma unroll
  for (int gg = 0; gg < 3; ++gg) {
    const int go = (gg == 0) ? 0 : ((gg == 1) ? 2048 : 3072);
    c1r[gg] = b1[b + go] + dotw(Wi1 + (size_t)(b + go) * 2048, W0b, lane);
    c2r[gg] = b2[b + go] + dotw(Wi2 + (size_t)(b + go) * 2048, W1b, lane);
    c3r[gg] = b3[b + go] + dotw(Wi3 + (size_t)(b + go) * 1024, W2b, lane);
  }
  {
    float* pc = (float*)(priv + PCS);
    if (lane == 0) {
#pragma unroll
      for (int gg = 0; gg < 3; ++gg) {
        cst1(pc + gg, c1r[gg]); cst1(pc + 3 + gg, c2r[gg]); cst1(pc + 6 + gg, c3r[gg]);
      }
    }
  }
  // A0 = Wi1_L @ W0 (3x56) for this row; keep in regs for init
  float A0 = 0.f, A1 = 0.f, A2 = 0.f;
  {
    const float* wr0 = Wi1 + (size_t)b * 2048;
    const float* wr1 = Wi1 + (size_t)(b + 2048) * 2048;
    const float* wr2 = Wi1 + (size_t)(b + 3072) * 2048;
    if (lane < CC) {
#pragma unroll 4
      for (int k = 0; k < 1024; ++k) {
        float w0 = W0w[k * CC + lane];
        A0 = fmaf(wr0[k], w0, A0);
        A1 = fmaf(wr1[k], w0, A1);
        A2 = fmaf(wr2[k], w0, A2);
      }
      float* pa = (float*)(priv + PA0);
      cst1(pa + 0 * CC + lane, A0);
      cst1(pa + 1 * CC + lane, A1);
      cst1(pa + 2 * CC + lane, A2);
    }
  }
  // W1R / W2R gate rows -> private bf16 (agent)
#pragma unroll
  for (int gg = 0; gg < 3; ++gg) {
    const int go = (gg == 0) ? 0 : ((gg == 1) ? 2048 : 3072);
    const float4* s1p = (const float4*)(Wi1 + (size_t)(b + go) * 2048 + 1024);
    const float4* s2p = (const float4*)(Wi2 + (size_t)(b + go) * 2048 + 1024);
    unsigned* d1 = (unsigned*)(priv + PW1R + gg * 1024);
    unsigned* d2 = (unsigned*)(priv + PW2R + gg * 1024);
#pragma unroll
    for (int u = 0; u < 4; ++u) {
      float4 x = s1p[lane * 4 + u];
      cstu2(d1 + 2 * (lane * 4 + u), bfp(x.x, x.y), bfp(x.z, x.w));
      float4 y = s2p[lane * 4 + u];
      cstu2(d2 + 2 * (lane * 4 + u), bfp(y.x, y.y), bfp(y.z, y.w));
    }
  }
  // V2/V3 (and V1 for b<56) rows -> private bf16
  {
    const float4* v2p = (const float4*)(V2w + (size_t)b * 1024);
    const float4* v3p = (const float4*)(V3w + (size_t)b * 1024);
    unsigned* d2 = (unsigned*)(priv + PV2);
    unsigned* d3 = (unsigned*)(priv + PV3);
#pragma unroll
    for (int u = 0; u < 4; ++u) {
      float4 a = v2p[lane * 4 + u]; cstu2(d2 + 2 * (lane * 4 + u), bfp(a.x, a.y), bfp(a.z, a.w));
      float4 c = v3p[lane * 4 + u]; cstu2(d3 + 2 * (lane * 4 + u), bfp(c.x, c.y), bfp(c.z, c.w));
    }
    if (b < CC) {
      const float4* v1p = (const float4*)(V1w + (size_t)b * 1024);
      unsigned* d1 = (unsigned*)(priv + PV1);
#pragma unroll
      for (int u = 0; u < 4; ++u) {
        float4 a = v1p[lane * 4 + u]; cstu2(d1 + 2 * (lane * 4 + u), bfp(a.x, a.y), bfp(a.z, a.w));
      }
    }
  }
  // t=0 init: s1_0 = act(A0@x0 + c1); publish s1_0, TD1_0(par0), s3=0, TD2(par1)=0
  {
    float p0 = 0.f, p1 = 0.f, p2 = 0.f;
    if (lane < CC) {
      float xv = inp[lane];
      p0 = A0 * xv; p1 = A1 * xv; p2 = A2 * xv;
    }
    p0 = wredsum(p0); p1 = wredsum(p1); p2 = wredsum(p2);
    float s1v = sigm(p2 + c1r[2]) * ftanh(sigm(p0 + c1r[0]) * ftanh(p1 + c1r[1]));
    if (lane == 0) {
      cst1(fws + FS1 + b, s1v);
      cst1(fws + FTD1 + b, s1v);          // parity 0
      cst1(fws + FS3 + b, 0.f);
      cst1(fws + FTD2 + 1024 + b, 0.f);   // parity 1
    }
    if (b == 0) {
      float ax = (lane < CC) ? fabsf(inp[lane]) : 0.f;
      l0 += wredsum(ax);                  // |nTD0_0| = sum|x_0|
    }
  }
  wwait(iws, 1, b, 16);

  // ======== phase 2: GEMMs M2 = Wi2_L@W1, M3 = Wi3@W2 -> private bf16 (agent)
  {
#pragma unroll
    for (int w = 0; w < 3; ++w) {
      const int go = (w == 0) ? 0 : ((w == 1) ? 2048 : 3072);
      const float4* a2 = (const float4*)(Wi2 + (size_t)(b + go) * 2048);
      const float4* a3 = (const float4*)(Wi3 + (size_t)(b + go) * 1024);
#pragma unroll
      for (int u = 0; u < 4; ++u) {
        ((float4*)arow[w])[lane * 4 + u]     = a2[lane * 4 + u];
        ((float4*)arow[3 + w])[lane * 4 + u] = a3[lane * 4 + u];
      }
    }
    __syncthreads();
    gemm48((const uint4*)w1bf, arow[0], arow[1], arow[2], priv + PM2, lane);
    gemm48((const uint4*)w2bf, arow[3], arow[4], arow[5], priv + PM3, lane);
  }
  warr(iws, 2, b);

  // ======== blocks >= LBLK are prologue-only
  if (b >= LBLK) return;

  // loop-block setup: 4 rows b+256j; param biases are race-free to read now
  unsigned short* prj[4];
#pragma unroll
  for (int j = 0; j < 4; ++j)
    prj[j] = (unsigned short*)(ws + OFF_PRIV + (size_t)(b + LBLK * j) * PRIVB);
  float v2br[4], v3br[4];
#pragma unroll
  for (int j = 0; j < 4; ++j) { v2br[j] = V2b[b + LBLK * j]; v3br[j] = V3b[b + LBLK * j]; }
  const float v1br = (b < CC) ? V1b[b] : 0.f;

  float cs1r[4][3], cs2r[4][3], cs3r[4][3];
  int g = 2;

  for (int t = 0; t < TT; ++t) {
    const int par = t & 1;
    float* td1cur = fws + FTD1 + par * 1024;
    float* td1nxt = fws + FTD1 + (par ^ 1) * 1024;
    float* td2old = fws + FTD2 + (par ^ 1) * 1024;
    float* td2cur = fws + FTD2 + par * 1024;

    // ---- pre-X: W2R @ TD2_{t-1} (parity-stable; zero vector at t=0 -> skip)
    float pp[4][3];
    if (t > 0) {
      float4 o0 = cld4(td2old + 16 * lane);
      float4 o1 = cld4(td2old + 16 * lane + 4);
      float4 o2 = cld4(td2old + 16 * lane + 8);
      float4 o3 = cld4(td2old + 16 * lane + 12);
#pragma unroll
      for (int j = 0; j < 4; ++j) {
        const unsigned short* wp = prj[j] + PW2R;
#pragma unroll
        for (int gg = 0; gg < 3; ++gg) pp[j][gg] = DOT16(wp, gg * 128, o0, o1, o2, o3);
      }
    } else {
#pragma unroll
      for (int j = 0; j < 4; ++j)
#pragma unroll
        for (int gg = 0; gg < 3; ++gg) pp[j][gg] = 0.f;
    }

    wwait(iws, g, b, (g == 2) ? 16 : 4);
    if (t == 0) {            // GEMM barrier passed: cs constants now visible
#pragma unroll
      for (int j = 0; j < 4; ++j) {
        const float* pc = (const float*)(prj[j] + PCS);
#pragma unroll
        for (int gg = 0; gg < 3; ++gg) {
          cs1r[j][gg] = pc[gg]; cs2r[j][gg] = pc[3 + gg]; cs3r[j][gg] = pc[6 + gg];
        }
      }
    }

    // ---- X_t: s2 = act(M2@TD1_t + W2R@TD2_{t-1} + c2); TD2_t; rc1_t; loss |TD1_t|
    float4 vt0 = cld4(td1cur + 16 * lane);
    float4 vt1 = cld4(td1cur + 16 * lane + 4);
    float4 vt2 = cld4(td1cur + 16 * lane + 8);
    float4 vt3 = cld4(td1cur + 16 * lane + 12);
    {
      float4 s30 = cld4(fws + FS3 + 16 * lane);
      float4 s31 = cld4(fws + FS3 + 16 * lane + 4);
      float4 s32 = cld4(fws + FS3 + 16 * lane + 8);
      float4 s33 = cld4(fws + FS3 + 16 * lane + 12);
      float xz[4][3], xv3[4];
#pragma unroll
      for (int j = 0; j < 4; ++j) {
        const unsigned short* pm = prj[j] + PM2;
#pragma unroll
        for (int gg = 0; gg < 3; ++gg) xz[j][gg] = DOT16(pm, gg * 128, vt0, vt1, vt2, vt3);
        xv3[j] = DOT16(prj[j] + PV3, 0, s30, s31, s32, s33);
      }
      float xv1 = 0.f;
      if (b < CC) {
        float4 u0 = cld4(fws + FS1 + 16 * lane);
        float4 u1 = cld4(fws + FS1 + 16 * lane + 4);
        float4 u2 = cld4(fws + FS1 + 16 * lane + 8);
        float4 u3 = cld4(fws + FS1 + 16 * lane + 12);
        xv1 = DOT16(priv + PV1, 0, u0, u1, u2, u3);
      }
      if (b == 0)
        l1 += wredsum(asum4(vt0) + asum4(vt1) + asum4(vt2) + asum4(vt3));
#pragma unroll
      for (int j = 0; j < 4; ++j) {
        float zi = xz[j][0] + pp[j][0] + cs2r[j][0];
        float zg = xz[j][1] + pp[j][1] + cs2r[j][1];
        float zo = xz[j][2] + pp[j][2] + cs2r[j][2];
        float s2v = sigm(zo) * ftanh(sigm(zi) * ftanh(zg));
        float rc3v = (t == 0) ? 0.f : (xv3[j] + v3br[j]);
        if (lane == 0) {
          cst1(fws + FS2 + b + LBLK * j, s2v);
          cst1(td2cur + b + LBLK * j, s2v - rc3v);
        }
      }
      if (b < CC && lane == 0) cst1(fws + FRC1 + b, xv1 + v1br);
    }
    warr(iws, ++g, b);

    // ---- pre-Y: W1R @ TD1_t (reuse register copy of TD1_t)
    float py[4][3];
#pragma unroll
    for (int j = 0; j < 4; ++j) {
      const unsigned short* wp = prj[j] + PW1R;
#pragma unroll
      for (int gg = 0; gg < 3; ++gg) py[j][gg] = DOT16(wp, gg * 128, vt0, vt1, vt2, vt3);
    }
    wwait(iws, g, b, 4);

    // ---- Y_t: s3_t = act(M3@TD2_t + c3); s1_{t+1} = act(A0@nTD0_{t+1} + W1R@TD1_t + c1);
    //           TD1_{t+1} = s1_{t+1} - (V2@s2_t + v2b); losses |TD2_t|, |nTD0_{t+1}|
    {
      float4 d0 = cld4(td2cur + 16 * lane);
      float4 d1 = cld4(td2cur + 16 * lane + 4);
      float4 d2 = cld4(td2cur + 16 * lane + 8);
      float4 d3 = cld4(td2cur + 16 * lane + 12);
      float4 e0 = cld4(fws + FS2 + 16 * lane);
      float4 e1 = cld4(fws + FS2 + 16 * lane + 4);
      float4 e2 = cld4(fws + FS2 + 16 * lane + 8);
      float4 e3 = cld4(fws + FS2 + 16 * lane + 12);
      float nd = 0.f;
      const int tn = (t < TT - 1) ? (t + 1) : (TT - 1);
      if (lane < CC) {
        float xv = inp[tn * CC + lane];
        float rcv = cld1(fws + FRC1 + lane);
        nd = xv - rcv;
      }
      float yz[4][3], yv2[4], pa[4][3];
#pragma unroll
      for (int j = 0; j < 4; ++j) {
        const unsigned short* pm = prj[j] + PM3;
#pragma unroll
        for (int gg = 0; gg < 3; ++gg) yz[j][gg] = DOT16(pm, gg * 128, d0, d1, d2, d3);
        yv2[j] = DOT16(prj[j] + PV2, 0, e0, e1, e2, e3);
        const float* pa0 = (const float*)(prj[j] + PA0);
#pragma unroll
        for (int gg = 0; gg < 3; ++gg)
          pa[j][gg] = wredsum((lane < CC) ? pa0[gg * CC + lane] * nd : 0.f);
      }
      if (b == 0) {
        l2 += wredsum(asum4(d0) + asum4(d1) + asum4(d2) + asum4(d3));
        if (t < TT - 1) l0 += wredsum((lane < CC) ? fabsf(nd) : 0.f);
      }
#pragma unroll
      for (int j = 0; j < 4; ++j) {
        float z3i = yz[j][0] + cs3r[j][0];
        float z3g = yz[j][1] + cs3r[j][1];
        float z3o = yz[j][2] + cs3r[j][2];
        float s3v = sigm(z3o) * ftanh(sigm(z3i) * ftanh(z3g));
        float rc2 = yv2[j] + v2br[j];
        float z1i = pa[j][0] + py[j][0] + cs1r[j][0];
        float z1g = pa[j][1] + py[j][1] + cs1r[j][1];
        float z1o = pa[j][2] + py[j][2] + cs1r[j][2];
        float s1n = sigm(z1o) * ftanh(sigm(z1i) * ftanh(z1g));
        if (lane == 0) {
          cst1(fws + FS3 + b + LBLK * j, s3v);
          cst1(fws + FS1 + b + LBLK * j, s1n);
          cst1(td1nxt + b + LBLK * j, s1n - rc2);
        }
      }
    }
    warr(iws, ++g, b);
  }

  if (b == 0 && lane == 0) out[0] = l0 + lam * l1 + lam2 * l2;
}

extern "C" void kernel_launch(void* const* d_in, const int* in_sizes, int n_in,
                              void* d_out, int out_size, void* d_ws, size_t ws_size,
                              hipStream_t stream) {
  const float* inp = (const float*)d_in[0];
  const float* W0w = (const float*)d_in[1];
  const float* W0b = (const float*)d_in[2];
  const float* W1w = (const float*)d_in[3];
  const float* W1b = (const float*)d_in[4];
  const float* W2w = (const float*)d_in[5];
  const float* W2b = (const float*)d_in[6];
  const float* Wi1 = (const float*)d_in[7];
  const float* b1  = (const float*)d_in[8];
  const float* Wi2 = (const float*)d_in[9];
  const float* b2  = (const float*)d_in[10];
  const float* Wi3 = (const float*)d_in[11];
  const float* b3  = (const float*)d_in[12];
  const float* V1w = (const float*)d_in[13];
  const float* V1b = (const float*)d_in[14];
  const float* V2w = (const float*)d_in[15];
  const float* V2b = (const float*)d_in[16];
  const float* V3w = (const float*)d_in[17];
  const float* V3b = (const float*)d_in[18];
  const int*   itn = (const int*)d_in[19];

  hipLaunchKernelGGL(predcells, dim3(GRID), dim3(NT), 0, stream,
                     inp, W0w, W0b, W1w, W1b, W2w, W2b,
                     Wi1, b1, Wi2, b2, Wi3, b3,
                     V1w, V1b, V2w, V2b, V3w, V3b, itn,
                     (float*)d_out, (char*)d_ws);
}

// Round 2
// 1473.521 us; speedup vs baseline: 1.4058x; 1.4058x over previous
//
#include <hip/hip_runtime.h>

#define CC 56
#define TT 64
#define GRID 1024
#define NT 256
#define NFLAG 64
#define SS 32                    // 128 B stride between sync slots
#define FB (GRID * SS)           // flag base (int index)
#define AGENT __HIP_MEMORY_SCOPE_AGENT

// ---- ws byte offsets
#define OFF_FWS   147456         // carry vectors (tagged {val,gen} 8B slots)
#define OFF_W1BF  262144         // W1 bf16, 2 MB
#define OFF_W2BF  2359296       // W2 bf16, 2 MB
#define OFF_PRIV  4456448       // 1024 × 32 KB private regions
#define PRIVB     32768

// ---- private region offsets (ushort units)
#define PM2  0                   // M2 rows (i,g,o) 3×1024 bf16
#define PM3  3072
#define PW1R 6144                // Wi1 right-half rows
#define PW2R 9216                // Wi2 right-half rows
#define PV2  12288
#define PV3  13312
#define PV1  14336
#define PA0  15360               // A0 fp32 3×56 at byte 30720

// ---- fws float offsets: tagged slots, 2 floats each {val, gen}
#define GS1   0                  // 1024 slots
#define GS2   2048
#define GS3   4096
#define GTD1  6144               // two parity slots 6144/8192
#define GTD2  10240              // two parity slots 10240/12288
#define GRC1  14336              // 56 slots

#define PGUARD (1 << 20)

static __device__ __forceinline__ float wredsum(float v) {
#pragma unroll
  for (int m = 32; m; m >>= 1) v += __shfl_xor(v, m, 64);
  return v;
}
static __device__ __forceinline__ float sigm(float x) { return 1.f / (1.f + __expf(-x)); }
static __device__ __forceinline__ float ftanh(float x) {
  x = fminf(15.f, fmaxf(-15.f, x));
  float e = __expf(2.f * x);
  return (e - 1.f) / (e + 1.f);
}

// coherent accessors (agent-scope) for repeatedly-rewritten data
static __device__ __forceinline__ float2 cld2(const float* p) {
  unsigned long long u = __hip_atomic_load((const unsigned long long*)p, __ATOMIC_RELAXED, AGENT);
  union { unsigned long long u; float2 f; } c; c.u = u; return c.f;
}
static __device__ __forceinline__ void cstu2(unsigned* p, unsigned a, unsigned b) {
  unsigned long long u = (unsigned long long)a | ((unsigned long long)b << 32);
  __hip_atomic_store((unsigned long long*)p, u, __ATOMIC_RELAXED, AGENT);
}
static __device__ __forceinline__ int ldi(const int* p) {
  return __hip_atomic_load(p, __ATOMIC_RELAXED, AGENT);
}
static __device__ __forceinline__ void sti(int* p, int v) {
  __hip_atomic_store(p, v, __ATOMIC_RELAXED, AGENT);
}

// ---- tagged-slot publish/poll. Slot = {fp32 val, int32 gen} in one 8B word.
// Poison 0xAAAAAAAA reads as negative gen; gens are small positive; monotone.
static __device__ __forceinline__ int ptag(float2 v) { return (int)__float_as_uint(v.y); }
static __device__ __forceinline__ void pub(float* base, int i, float v, int tag) {
  cstu2((unsigned*)(base + 2 * i), __float_as_uint(v), (unsigned)tag);
}
static __device__ __forceinline__ float4 poll4(const float* base, int i0, int want) {
  const float* p = base + 2 * i0;
  float2 a, b, c, d; int gd = 0;
  for (;;) {
    a = cld2(p); b = cld2(p + 2); c = cld2(p + 4); d = cld2(p + 6);
    if (ptag(a) >= want && ptag(b) >= want && ptag(c) >= want && ptag(d) >= want) break;
    if (++gd > PGUARD) break;   // convert tag bugs into wrong-answer, not hang
  }
  return make_float4(a.x, b.x, c.x, d.x);
}
static __device__ __forceinline__ float poll1(const float* base, int i, int want) {
  const float* p = base + 2 * i;
  float2 a; int gd = 0;
  for (;;) {
    a = cld2(p);
    if (ptag(a) >= want) break;
    if (++gd > PGUARD) break;
  }
  return a.x;
}

// bf16 pack (RNE) + dot helpers
static __device__ __forceinline__ unsigned bfp(float lo, float hi) {
  unsigned a = __float_as_uint(lo), b = __float_as_uint(hi);
  a = (a + 0x7fffu + ((a >> 16) & 1u)) >> 16;
  b = (b + 0x7fffu + ((b >> 16) & 1u)) >> 16;
  return a | (b << 16);
}
static __device__ __forceinline__ float blo(unsigned u) { return __uint_as_float(u << 16); }
static __device__ __forceinline__ float bhi(unsigned u) { return __uint_as_float(u & 0xffff0000u); }
static __device__ __forceinline__ float bdot2(uint2 w, float4 v) {
  float r = blo(w.x) * v.x;
  r = fmaf(bhi(w.x), v.y, r);
  r = fmaf(blo(w.y), v.z, r);
  r = fmaf(bhi(w.y), v.w, r);
  return r;
}
static __device__ __forceinline__ float asum4(float4 v) {
  return fabsf(v.x) + fabsf(v.y) + fabsf(v.z) + fabsf(v.w);
}

// prologue master-relay barrier (verified). No init: 0xAA poison < 0, g monotone > 0.
static __device__ __forceinline__ void warr(int* iws, int g, int b) {
  __syncthreads();
  if (threadIdx.x == 0) sti(iws + SS * b, g);
}
static __device__ __forceinline__ void wwait(int* iws, int g, int b) {
  if (b == 0) {
    const int* p0 = iws + SS * threadIdx.x;
    for (;;) {
      int a0 = ldi(p0), a1 = ldi(p0 + SS * 256), a2 = ldi(p0 + SS * 512), a3 = ldi(p0 + SS * 768);
      if (a0 >= g && a1 >= g && a2 >= g && a3 >= g) break;
      __builtin_amdgcn_s_sleep(1);
    }
    __syncthreads();
    if (threadIdx.x < NFLAG) sti(iws + FB + SS * threadIdx.x, g);
  } else {
    if (threadIdx.x == 0)
      while (ldi(iws + FB + SS * (b & (NFLAG - 1))) < g) __builtin_amdgcn_s_sleep(1);
  }
  __asm__ __volatile__("" ::: "memory");
  __syncthreads();
}

// 1024-dot: wave-local, 16 fp32/lane (used for prologue constants)
static __device__ __forceinline__ float dotw(const float* a, const float* c, int lane) {
  const float4* a4 = (const float4*)a;
  const float4* c4 = (const float4*)c;
  float acc = 0.f;
#pragma unroll
  for (int j = 0; j < 4; ++j) {
    float4 x = a4[lane * 4 + j], y = c4[lane * 4 + j];
    acc = fmaf(x.x, y.x, fmaf(x.y, y.y, fmaf(x.z, y.z, fmaf(x.w, y.w, acc))));
  }
  return wredsum(acc);
}

__global__ void __launch_bounds__(NT, 4) predcells(
    const float* __restrict__ inp,
    const float* __restrict__ W0w, const float* __restrict__ W0b,
    const float* __restrict__ W1w, const float* __restrict__ W1b,
    const float* __restrict__ W2w, const float* __restrict__ W2b,
    const float* __restrict__ Wi1, const float* __restrict__ b1,
    const float* __restrict__ Wi2, const float* __restrict__ b2,
    const float* __restrict__ Wi3, const float* __restrict__ b3,
    const float* __restrict__ V1w, const float* __restrict__ V1b,
    const float* __restrict__ V2w, const float* __restrict__ V2b,
    const float* __restrict__ V3w, const float* __restrict__ V3b,
    const int* __restrict__ itn,
    float* __restrict__ out, char* ws)
{
  const int tid = threadIdx.x;
  const int lane = tid & 63;
  const int wv = tid >> 6;
  const int b = blockIdx.x;
  const bool hasV1 = (b < CC);

  int* iws = (int*)ws;
  float* fws = (float*)(ws + OFF_FWS);
  unsigned short* w1bf = (unsigned short*)(ws + OFF_W1BF);
  unsigned short* w2bf = (unsigned short*)(ws + OFF_W2BF);
  unsigned short* priv = (unsigned short*)(ws + OFF_PRIV + (size_t)b * PRIVB);

  __shared__ float arow[6][1024];           // GEMM staging (24 KB)
  __shared__ float psX[6][4], psP[3][4], psA[3];
  __shared__ float cs1[3], cs2[3], cs3[3];

  const int gofs = (wv == 0) ? 0 : ((wv == 1) ? 2048 : 3072);  // i,g,o rows for waves 0..2

  // ======== phase 0: convert W1/W2 row b to shared bf16 (coherent stores)
  {
    float4 r1 = ((const float4*)(W1w + (size_t)b * 1024))[tid];
    cstu2((unsigned*)(w1bf + (size_t)b * 1024 + 4 * tid), bfp(r1.x, r1.y), bfp(r1.z, r1.w));
    float4 r2 = ((const float4*)(W2w + (size_t)b * 1024))[tid];
    cstu2((unsigned*)(w2bf + (size_t)b * 1024 + 4 * tid), bfp(r2.x, r2.y), bfp(r2.z, r2.w));
  }
  warr(iws, 1, b);

  // ======== phase 1 (during barrier-1 window): local prep
  const float lam = (itn[0] <= 1000) ? 1e-4f : 1e-2f;
  const float lam2 = lam * lam;
  const float v1b_b = hasV1 ? V1b[b] : 0.f;
  const float v2b_b = V2b[b];
  const float v3b_b = V3b[b];
  float l0 = 0.f, l1 = 0.f, l2 = 0.f;  // loss partials, block0 registers

  if (wv < 3) {
    // constants c1/c2/c3 per gate row
    float c1v = b1[b + gofs] + dotw(Wi1 + (size_t)(b + gofs) * 2048, W0b, lane);
    float c2v = b2[b + gofs] + dotw(Wi2 + (size_t)(b + gofs) * 2048, W1b, lane);
    float c3v = b3[b + gofs] + dotw(Wi3 + (size_t)(b + gofs) * 1024, W2b, lane);
    if (lane == 0) { cs1[wv] = c1v; cs2[wv] = c2v; cs3[wv] = c3v; }
    // A0 = Wi1_L @ W0 (3×56): lanes own columns, k-loop broadcast
    if (lane < CC) {
      const float* wr = Wi1 + (size_t)(b + gofs) * 2048;
      float acc = 0.f;
      for (int k = 0; k < 1024; ++k) acc = fmaf(wr[k], W0w[k * CC + lane], acc);
      ((float*)(priv + PA0))[wv * CC + lane] = acc;
    }
    // private bf16: Wi1R / Wi2R gate rows (plain — own block reads only)
    {
      float4 x = ((const float4*)(Wi1 + (size_t)(b + gofs) * 2048 + 1024))[lane];
      ((uint2*)(priv + PW1R + wv * 1024))[lane] = make_uint2(bfp(x.x, x.y), bfp(x.z, x.w));
      float4 y = ((const float4*)(Wi2 + (size_t)(b + gofs) * 2048 + 1024))[lane];
      ((uint2*)(priv + PW2R + wv * 1024))[lane] = make_uint2(bfp(y.x, y.y), bfp(y.z, y.w));
    }
  } else {
    // wave 3: V2/V3/V1 rows to private bf16 (256 f4-chunks / 64 lanes = 4 each)
#pragma unroll
    for (int j = 0; j < 4; ++j) {
      int i = lane * 4 + j;
      float4 a = ((const float4*)(V2w + (size_t)b * 1024))[i];
      ((uint2*)(priv + PV2))[i] = make_uint2(bfp(a.x, a.y), bfp(a.z, a.w));
      float4 c = ((const float4*)(V3w + (size_t)b * 1024))[i];
      ((uint2*)(priv + PV3))[i] = make_uint2(bfp(c.x, c.y), bfp(c.z, c.w));
      if (hasV1) {
        float4 d = ((const float4*)(V1w + (size_t)b * 1024))[i];
        ((uint2*)(priv + PV1))[i] = make_uint2(bfp(d.x, d.y), bfp(d.z, d.w));
      }
    }
  }
  __syncthreads();
  // s1_0 = act(A0@x_0 + c1); publish tagged: s1_0, TD1_0(par0), s3=0, TD2(par1)=0, all gen=1
  if (wv < 3) {
    float p = 0.f, ax = 0.f;
    if (lane < CC) {
      float xv = inp[lane];
      p = ((const float*)(priv + PA0))[wv * CC + lane] * xv;
      ax = fabsf(xv);
    }
    p = wredsum(p);
    ax = wredsum(ax);
    if (lane == 0) psA[wv] = p;
    if (b == 0 && wv == 0) l0 += ax;   // |nTD0_0| = Σ|x_0|
  }
  __syncthreads();
  if (tid == 0) {
    float s1v = sigm(psA[2] + cs1[2]) * ftanh(sigm(psA[0] + cs1[0]) * ftanh(psA[1] + cs1[1]));
    pub(fws + GS1, b, s1v, 1);
    pub(fws + GTD1, b, s1v, 1);          // parity 0
    pub(fws + GS3, b, 0.f, 1);
    pub(fws + GTD2 + 2048, b, 0.f, 1);   // parity 1 (read by pre-X_0)
  }
  wwait(iws, 1, b);

  // ======== phase 2: GEMMs M2 = Wi2_L@W1, M3 = Wi3@W2 → private bf16 (plain)
  {
#pragma unroll
    for (int w = 0; w < 3; ++w) {
      int go = (w == 0) ? 0 : ((w == 1) ? 2048 : 3072);
      ((float4*)arow[w])[tid]     = ((const float4*)(Wi2 + (size_t)(b + go) * 2048))[tid];
      ((float4*)arow[3 + w])[tid] = ((const float4*)(Wi3 + (size_t)(b + go) * 1024))[tid];
    }
    __syncthreads();
    float ac[12];
#pragma unroll
    for (int j = 0; j < 12; ++j) ac[j] = 0.f;
    const uint2* wsrc = (const uint2*)w1bf;
#pragma unroll 4
    for (int k = 0; k < 1024; ++k) {
      uint2 wp = wsrc[k * 256 + tid];
      float f0 = blo(wp.x), f1 = bhi(wp.x), f2 = blo(wp.y), f3 = bhi(wp.y);
      float ai = arow[0][k], ag = arow[1][k], ao = arow[2][k];
      ac[0] = fmaf(ai, f0, ac[0]); ac[1] = fmaf(ai, f1, ac[1]); ac[2] = fmaf(ai, f2, ac[2]); ac[3] = fmaf(ai, f3, ac[3]);
      ac[4] = fmaf(ag, f0, ac[4]); ac[5] = fmaf(ag, f1, ac[5]); ac[6] = fmaf(ag, f2, ac[6]); ac[7] = fmaf(ag, f3, ac[7]);
      ac[8] = fmaf(ao, f0, ac[8]); ac[9] = fmaf(ao, f1, ac[9]); ac[10] = fmaf(ao, f2, ac[10]); ac[11] = fmaf(ao, f3, ac[11]);
    }
#pragma unroll
    for (int w = 0; w < 3; ++w)
      ((uint2*)(priv + PM2 + w * 1024))[tid] =
          make_uint2(bfp(ac[w * 4 + 0], ac[w * 4 + 1]), bfp(ac[w * 4 + 2], ac[w * 4 + 3]));
#pragma unroll
    for (int j = 0; j < 12; ++j) ac[j] = 0.f;
    wsrc = (const uint2*)w2bf;
#pragma unroll 4
    for (int k = 0; k < 1024; ++k) {
      uint2 wp = wsrc[k * 256 + tid];
      float f0 = blo(wp.x), f1 = bhi(wp.x), f2 = blo(wp.y), f3 = bhi(wp.y);
      float ai = arow[3][k], ag = arow[4][k], ao = arow[5][k];
      ac[0] = fmaf(ai, f0, ac[0]); ac[1] = fmaf(ai, f1, ac[1]); ac[2] = fmaf(ai, f2, ac[2]); ac[3] = fmaf(ai, f3, ac[3]);
      ac[4] = fmaf(ag, f0, ac[4]); ac[5] = fmaf(ag, f1, ac[5]); ac[6] = fmaf(ag, f2, ac[6]); ac[7] = fmaf(ag, f3, ac[7]);
      ac[8] = fmaf(ao, f0, ac[8]); ac[9] = fmaf(ao, f1, ac[9]); ac[10] = fmaf(ao, f2, ac[10]); ac[11] = fmaf(ao, f3, ac[11]);
    }
#pragma unroll
    for (int w = 0; w < 3; ++w)
      ((uint2*)(priv + PM3 + w * 1024))[tid] =
          make_uint2(bfp(ac[w * 4 + 0], ac[w * 4 + 1]), bfp(ac[w * 4 + 2], ac[w * 4 + 3]));
  }
  // No g=2 barrier: loop entry is self-paced by data tags.

  // ======== recurrent loop: zero barriers; per-element generation tags
  const uint2* pm2 = (const uint2*)(priv + PM2);
  const uint2* pm3 = (const uint2*)(priv + PM3);
  const uint2* pw1r = (const uint2*)(priv + PW1R);
  const uint2* pw2r = (const uint2*)(priv + PW2R);
  const uint2* pv2 = (const uint2*)(priv + PV2);
  const uint2* pv3 = (const uint2*)(priv + PV3);
  const uint2* pv1 = (const uint2*)(priv + PV1);
  const float* a0p = (const float*)(priv + PA0);

  for (int t = 0; t < TT; ++t) {
    const int par = t & 1;
    float* td1cur = fws + GTD1 + par * 2048;         // TD1_t
    float* td1nxt = fws + GTD1 + (par ^ 1) * 2048;   // TD1_{t+1}
    float* td2old = fws + GTD2 + (par ^ 1) * 2048;   // TD2_{t-1}
    float* td2cur = fws + GTD2 + par * 2048;         // TD2_t
    // expected / published generation tags (write-count per slot; verified t=0..3 by hand)
    const int w_old = (t + 2) >> 1;                  // TD2_{t-1} in pre-X
    const int w_td1 = (t >> 1) + 1;                  // TD1_t in X
    const int w_s   = t + 1;                         // S1,S3 (X); S2,RC1 (Y)
    const int w_cur = ((t + 2) >> 1) + (t & 1);      // TD2_t in Y
    const int p_td  = (t & 1) ? ((t + 3) >> 1) : ((t >> 1) + 1); // TD2[par] (X) & TD1[par^1] (Y)

    // ---- pre-X: W2R @ TD2_{t-1} (available: all X_{t-1} gated our Y_{t-1})
    uint2 wm2[3]; wm2[0] = pm2[tid]; wm2[1] = pm2[256 + tid]; wm2[2] = pm2[512 + tid];
    uint2 wv3 = pv3[tid];
    uint2 wv1; if (hasV1) wv1 = pv1[tid];
    {
      float4 v = poll4(td2old, 4 * tid, w_old);
      uint2 wr0 = pw2r[tid], wr1 = pw2r[256 + tid], wr2 = pw2r[512 + tid];
      float p0 = wredsum(bdot2(wr0, v));
      float p1 = wredsum(bdot2(wr1, v));
      float p2 = wredsum(bdot2(wr2, v));
      if (lane == 0) { psP[0][wv] = p0; psP[1][wv] = p1; psP[2][wv] = p2; }
    }
    // ---- X_t: s2_t = act(M2@TD1_t + Wi2R@TD2_{t-1} + c2); TD2_t; rc1_t; loss|TD1_t|
    float4 vtd1 = poll4(td1cur, 4 * tid, w_td1);     // kept in regs for pre-Y
    {
      float4 vs3 = poll4(fws + GS3, 4 * tid, w_s);
      float p0 = wredsum(bdot2(wm2[0], vtd1));
      float p1 = wredsum(bdot2(wm2[1], vtd1));
      float p2 = wredsum(bdot2(wm2[2], vtd1));
      float p3 = wredsum(bdot2(wv3, vs3));
      if (lane == 0) { psX[0][wv] = p0; psX[1][wv] = p1; psX[2][wv] = p2; psX[3][wv] = p3; }
      if (hasV1) {
        float4 vs1 = poll4(fws + GS1, 4 * tid, w_s);
        float pv = wredsum(bdot2(wv1, vs1));
        if (lane == 0) psX[4][wv] = pv;
      }
      if (b == 0) {
        float al = wredsum(asum4(vtd1));
        if (lane == 0) psX[5][wv] = al;
      }
      __syncthreads();
      if (tid == 0) {
        float zi = psX[0][0] + psX[0][1] + psX[0][2] + psX[0][3] + psP[0][0] + psP[0][1] + psP[0][2] + psP[0][3] + cs2[0];
        float zg = psX[1][0] + psX[1][1] + psX[1][2] + psX[1][3] + psP[1][0] + psP[1][1] + psP[1][2] + psP[1][3] + cs2[1];
        float zo = psX[2][0] + psX[2][1] + psX[2][2] + psX[2][3] + psP[2][0] + psP[2][1] + psP[2][2] + psP[2][3] + cs2[2];
        float s2v = sigm(zo) * ftanh(sigm(zi) * ftanh(zg));
        float rc3v = (t == 0) ? 0.f : (psX[3][0] + psX[3][1] + psX[3][2] + psX[3][3] + v3b_b);
        pub(fws + GS2, b, s2v, w_s);
        pub(td2cur, b, s2v - rc3v, p_td);
        if (hasV1) pub(fws + GRC1, b, psX[4][0] + psX[4][1] + psX[4][2] + psX[4][3] + v1b_b, w_s);
        if (b == 0) l1 += psX[5][0] + psX[5][1] + psX[5][2] + psX[5][3];
      }
      __syncthreads();   // protect psP before pre-Y overwrites
    }

    // ---- pre-Y: W1R @ TD1_t (register copy; no re-poll)
    {
      uint2 wr0 = pw1r[tid], wr1 = pw1r[256 + tid], wr2 = pw1r[512 + tid];
      float p0 = wredsum(bdot2(wr0, vtd1));
      float p1 = wredsum(bdot2(wr1, vtd1));
      float p2 = wredsum(bdot2(wr2, vtd1));
      if (lane == 0) { psP[0][wv] = p0; psP[1][wv] = p1; psP[2][wv] = p2; }
    }
    // ---- Y_t: s3_t = act(M3@TD2_t + c3); s1_{t+1} = act(A0@nTD0_{t+1} + Wi1R@TD1_t + c1);
    //          TD1_{t+1} = s1_{t+1} − (V2@s2_t + v2b); losses |TD2_t|, |nTD0_{t+1}|
    {
      uint2 wm3[3]; wm3[0] = pm3[tid]; wm3[1] = pm3[256 + tid]; wm3[2] = pm3[512 + tid];
      uint2 wv2 = pv2[tid];
      float4 vtd2 = poll4(td2cur, 4 * tid, w_cur);
      float4 vs2  = poll4(fws + GS2, 4 * tid, w_s);
      float p0 = wredsum(bdot2(wm3[0], vtd2));
      float p1 = wredsum(bdot2(wm3[1], vtd2));
      float p2 = wredsum(bdot2(wm3[2], vtd2));
      float p3 = wredsum(bdot2(wv2, vs2));
      if (lane == 0) { psX[0][wv] = p0; psX[1][wv] = p1; psX[2][wv] = p2; psX[3][wv] = p3; }
      if (b == 0) {
        float al = wredsum(asum4(vtd2));
        if (lane == 0) psX[5][wv] = al;
      }
      // A0 gate dots over nTD0_{t+1} (x clamped at t=63; result unused there for loss)
      if (wv < 3) {
        const int tn = (t < TT - 1) ? (t + 1) : (TT - 1);
        float p = 0.f, ax = 0.f;
        if (lane < CC) {
          float xv = inp[tn * CC + lane];
          float rcv = poll1(fws + GRC1, lane, w_s);
          float ndv = xv - rcv;
          p = a0p[wv * CC + lane] * ndv;
          ax = fabsf(ndv);
        }
        p = wredsum(p);
        ax = wredsum(ax);
        if (lane == 0) psA[wv] = p;
        if (b == 0 && wv == 0 && t < TT - 1) l0 += ax;
      }
      __syncthreads();
      if (tid == 0) {
        float z3i = psX[0][0] + psX[0][1] + psX[0][2] + psX[0][3] + cs3[0];
        float z3g = psX[1][0] + psX[1][1] + psX[1][2] + psX[1][3] + cs3[1];
        float z3o = psX[2][0] + psX[2][1] + psX[2][2] + psX[2][3] + cs3[2];
        pub(fws + GS3, b, sigm(z3o) * ftanh(sigm(z3i) * ftanh(z3g)), t + 2);
        float rc2v = psX[3][0] + psX[3][1] + psX[3][2] + psX[3][3] + v2b_b;
        float z1i = psA[0] + psP[0][0] + psP[0][1] + psP[0][2] + psP[0][3] + cs1[0];
        float z1g = psA[1] + psP[1][0] + psP[1][1] + psP[1][2] + psP[1][3] + cs1[1];
        float z1o = psA[2] + psP[2][0] + psP[2][1] + psP[2][2] + psP[2][3] + cs1[2];
        float s1n = sigm(z1o) * ftanh(sigm(z1i) * ftanh(z1g));
        pub(fws + GS1, b, s1n, t + 2);
        pub(td1nxt, b, s1n - rc2v, p_td);
        if (b == 0) l2 += psX[5][0] + psX[5][1] + psX[5][2] + psX[5][3];
      }
      __syncthreads();   // protect psP/psX before next iteration overwrites
    }
  }

  if (b == 0 && tid == 0) out[0] = l0 + lam * l1 + lam2 * l2;
}

extern "C" void kernel_launch(void* const* d_in, const int* in_sizes, int n_in,
                              void* d_out, int out_size, void* d_ws, size_t ws_size,
                              hipStream_t stream) {
  const float* inp = (const float*)d_in[0];
  const float* W0w = (const float*)d_in[1];
  const float* W0b = (const float*)d_in[2];
  const float* W1w = (const float*)d_in[3];
  const float* W1b = (const float*)d_in[4];
  const float* W2w = (const float*)d_in[5];
  const float* W2b = (const float*)d_in[6];
  const float* Wi1 = (const float*)d_in[7];
  const float* b1  = (const float*)d_in[8];
  const float* Wi2 = (const float*)d_in[9];
  const float* b2  = (const float*)d_in[10];
  const float* Wi3 = (const float*)d_in[11];
  const float* b3  = (const float*)d_in[12];
  const float* V1w = (const float*)d_in[13];
  const float* V1b = (const float*)d_in[14];
  const float* V2w = (const float*)d_in[15];
  const float* V2b = (const float*)d_in[16];
  const float* V3w = (const float*)d_in[17];
  const float* V3b = (const float*)d_in[18];
  const int*   itn = (const int*)d_in[19];

  hipLaunchKernelGGL(predcells, dim3(GRID), dim3(NT), 0, stream,
                     inp, W0w, W0b, W1w, W1b, W2w, W2b,
                     Wi1, b1, Wi2, b2, Wi3, b3,
                     V1w, V1b, V2w, V2b, V3w, V3b, itn,
                     (float*)d_out, (char*)d_ws);
}